// Round 2
// baseline (192.293 us; speedup 1.0000x reference)
//
#include <hip/hip_runtime.h>
#include <hip/hip_bf16.h>

#define BATCH 8192
#define IDIM 256
#define ODIM 256
#define KGRID 64

#define NCHUNK 4
#define IPC 64            // i-values per K-chunk
#define BM 128
#define THREADS 512
#define RG_TOT 4096       // (2*IDIM*KGRID)/8

typedef __attribute__((ext_vector_type(8))) short short8;
typedef __attribute__((ext_vector_type(4))) float float4v;
typedef __attribute__((ext_vector_type(4))) unsigned int uint4v;

// pack two f32 -> (bf16(c) | bf16(s)<<16), RTNE
__device__ __forceinline__ unsigned int bf16pack(float c, float s) {
    union { float f; unsigned int u; } a, b;
    a.f = c; b.f = s;
    unsigned int ua = a.u + (0x7fffu + ((a.u >> 16) & 1u));
    unsigned int ub = b.u + (0x7fffu + ((b.u >> 16) & 1u));
    return (ua >> 16) | (ub & 0xffff0000u);
}

// W[2][256][256][64] f32  ->  Bw[rg=4096][j=256][8] bf16
__global__ void prep_w(const float4v* __restrict__ W, uint4v* __restrict__ Bw) {
    int tid = blockIdx.x * 256 + threadIdx.x;   // 1,048,576 threads
    int rg = tid >> 8;
    int j = tid & 255;
    float4v c4 = W[j * 4096 + rg];
    float4v s4 = W[1048576 + j * 4096 + rg];
    uint4v o;
    o.x = bf16pack(c4.x, s4.x);
    o.y = bf16pack(c4.y, s4.y);
    o.z = bf16pack(c4.z, s4.z);
    o.w = bf16pack(c4.w, s4.w);
    Bw[rg * 256 + j] = o;   // coalesced 16B stores, j fastest
}

// load one half-iteration (2 k-slots x 4 col-groups) of B into register buffer B
#define LOADHALF(B, S0) do {                                              \
    _Pragma("unroll") for (int q_ = 0; q_ < 2; ++q_) {                    \
        int s_ = (S0) + q_; if (s_ > 255) s_ = 255;                       \
        _Pragma("unroll") for (int f_ = 0; f_ < 4; ++f_)                  \
            B[q_ * 4 + f_] = Bp[(size_t)s_ * 1024 + f_ * 16];             \
    } } while (0)

__global__ __launch_bounds__(THREADS, 2) void kan_main(
    const float* __restrict__ x,
    const short* __restrict__ Bw,
    float* __restrict__ part)
{
    __shared__ __align__(16) short A_lds[2][16 * BM * 8];   // 64 KB, dbuf feature tiles

    const int bx = blockIdx.x;
    const int chunk = bx & 3;          // K-chunk 0..3
    const int mt = bx >> 2;            // M-tile 0..63
    const int b0 = mt * BM;
    const int i0 = chunk * IPC;
    const int t = threadIdx.x;
    const int lane = t & 63;
    const int wave = t >> 6;           // 0..7
    const int wm = wave >> 2;          // 0..1  (M half)
    const int wn = wave & 3;           // 0..3  (N quarter)

    const int row = t >> 2;            // 0..127  (feats row)
    const int sub = t & 3;             // 16 consecutive k's per thread

    // per-thread x pointer: x[(b0+row)*IDIM + i0 + iloc]
    const float* xp = x + (size_t)(b0 + row) * IDIM + i0;

    // features for one i -> Abuf laid out [16 rg][128 row][8 bf16]
    // thread covers k codes sub*16 .. sub*16+15 (mult = code+1), via angle recurrence
    auto feats = [&](short* Abuf, float xv) {
        float xk = xv * 0.15915494309189535f;   // revolutions per unit k
        float dr = xk - floorf(xk);
        float cd = __builtin_amdgcn_cosf(dr);   // cos(2*pi*x)
        float sd = __builtin_amdgcn_sinf(dr);
        float r0 = xk * (float)(sub * 16 + 1);
        r0 -= floorf(r0);
        float c = __builtin_amdgcn_cosf(r0);
        float s = __builtin_amdgcn_sinf(r0);
        uint4v* slotp = (uint4v*)Abuf + (sub * 4) * BM + row;
        #pragma unroll
        for (int g = 0; g < 4; ++g) {
            uint4v o;
            #pragma unroll
            for (int u = 0; u < 4; ++u) {
                union { __hip_bfloat162 h; unsigned int w; } cv;
                cv.h = __float22bfloat162_rn(make_float2(c, s));
                o[u] = cv.w;
                float cn = c * cd - s * sd;     // advance angle by x
                float sn = s * cd + c * sd;
                c = cn; s = sn;
            }
            slotp[g * BM] = o;
        }
    };

    // per-thread B pointer (16B slot granularity): slot = rg*256 + col
    const short8* Bp = (const short8*)Bw
        + (size_t)(chunk * 1024 + (lane >> 4)) * 256 + wn * 64 + (lane & 15);

    short8 bB[2][8];
    LOADHALF(bB[0], 0);   // s = 0,1  (iter 0, kk 0..1)
    LOADHALF(bB[1], 2);   // s = 2,3  (iter 0, kk 2..3)

    float xv = xp[0];
    feats(A_lds[0], xv);
    xv = xp[1];
    __syncthreads();

    float4v acc[4][4];
    #pragma unroll
    for (int m = 0; m < 4; ++m)
        #pragma unroll
        for (int f = 0; f < 4; ++f)
            acc[m][f] = (float4v)(0.0f);

    const int aoff = (lane >> 4) * BM + wm * 64 + (lane & 15);

    for (int it = 0; it < IPC; ++it) {
        const int cur = it & 1;
        const short8* Ab = (const short8*)A_lds[cur];
        #pragma unroll
        for (int kk = 0; kk < 4; ++kk) {
            short8 a[4];
            #pragma unroll
            for (int m = 0; m < 4; ++m)
                a[m] = Ab[(kk * 4) * BM + aoff + m * 16];
            #pragma unroll
            for (int m = 0; m < 4; ++m)
                #pragma unroll
                for (int f = 0; f < 4; ++f)
                    acc[m][f] = __builtin_amdgcn_mfma_f32_16x16x32_bf16(
                        a[m], bB[kk >> 1][(kk & 1) * 4 + f], acc[m][f], 0, 0, 0);
            if (kk == 1) { LOADHALF(bB[0], it * 4 + 4); }   // next iter kk 0..1
            if (kk == 3) { LOADHALF(bB[1], it * 4 + 6); }   // next iter kk 2..3
        }
        if (it + 1 < IPC) {
            feats(A_lds[cur ^ 1], xv);
            xv = xp[(it + 2 < IPC) ? (it + 2) : (IPC - 1)];
        }
        __syncthreads();
    }

    // ---- store partials: part[chunk][b][j] ----
    // C/D layout (m89): col = lane&15, row = (lane>>4)*4 + v
    float* pc = part + (size_t)chunk * (BATCH * ODIM)
              + (size_t)(b0 + wm * 64 + ((lane >> 4) * 4)) * ODIM
              + wn * 64 + (lane & 15);
    #pragma unroll
    for (int m = 0; m < 4; ++m)
        #pragma unroll
        for (int v = 0; v < 4; ++v)
            #pragma unroll
            for (int f = 0; f < 4; ++f)
                pc[(size_t)(m * 16 + v) * ODIM + f * 16] = acc[m][f][v];
}

__global__ void reduce_bias(const float4v* __restrict__ part,
                            const float4v* __restrict__ bias,
                            float4v* __restrict__ out)
{
    const int tid = blockIdx.x * 256 + threadIdx.x;   // 524288 float4s
    const int Q = BATCH * ODIM / 4;
    float4v r = part[tid] + part[tid + Q] + part[tid + 2 * Q] + part[tid + 3 * Q];
    r += bias[tid & 63];
    out[tid] = r;
}

extern "C" void kernel_launch(void* const* d_in, const int* in_sizes, int n_in,
                              void* d_out, int out_size, void* d_ws, size_t ws_size,
                              hipStream_t stream)
{
    const float* x = (const float*)d_in[0];
    const float* W = (const float*)d_in[1];
    const float* bias = (const float*)d_in[2];
    float* out = (float*)d_out;

    // workspace layout: Bw bf16 [4096][256][8] = 16.78 MB, then partials 33.55 MB
    short* Bw = (short*)d_ws;
    float* part = (float*)((char*)d_ws + (size_t)RG_TOT * 256 * 16);

    prep_w<<<4096, 256, 0, stream>>>((const float4v*)W, (uint4v*)Bw);
    kan_main<<<256, THREADS, 0, stream>>>(x, Bw, part);
    reduce_bias<<<(BATCH * ODIM / 4) / 256, 256, 0, stream>>>(
        (const float4v*)part, (const float4v*)bias, (float4v*)out);
}